// Round 1
// baseline (750.111 us; speedup 1.0000x reference)
//
#include <hip/hip_runtime.h>

// ---------- small helpers ----------
typedef __attribute__((ext_vector_type(8))) short bf16x8;
typedef __attribute__((ext_vector_type(4))) float f32x4;

__device__ __forceinline__ unsigned short f2bf(float x) {
  union { float f; unsigned u; } v; v.f = x;
  unsigned r = v.u + 0x7fffu + ((v.u >> 16) & 1u);
  return (unsigned short)(r >> 16);
}
__device__ __forceinline__ float bf2f(unsigned short s) {
  union { unsigned u; float f; } v; v.u = ((unsigned)s) << 16;
  return v.f;
}
__device__ __forceinline__ float sigm(float x) { return 1.f / (1.f + __expf(-x)); }

typedef const __attribute__((address_space(1))) void gvoid_t;
typedef __attribute__((address_space(3))) void lvoid_t;
__device__ __forceinline__ void gl16(const void* g, void* l) {
  __builtin_amdgcn_global_load_lds((gvoid_t*)g, (lvoid_t*)l, 16, 0, 0);
}

#define B_ 64
#define TDEC 63
#define D_ 512
#define V_ 10000
#define NWG 64

// ---------- kernel 1: encoder sum + bf16x3 A'' build ----------
// A'' layout: [128 rows][1536] bf16 = [hi(sum) | hi(sum) | lo(sum)], rows>=64 zeroed by prep.
__global__ __launch_bounds__(256) void enc_reduce(const float* __restrict__ enc,
                                                  unsigned short* __restrict__ App) {
  int b = blockIdx.x;
  int d = blockIdx.y * 256 + threadIdx.x;
  const float* p = enc + (long)b * 196 * 512 + d;
  float s = 0.f;
#pragma unroll 4
  for (int i = 0; i < 196; ++i) s += p[(long)i * 512];
  unsigned short hi = f2bf(s);
  unsigned short lo = f2bf(s - bf2f(hi));
  App[b * 1536 + d] = hi;
  App[b * 1536 + 512 + d] = hi;
  App[b * 1536 + 1024 + d] = lo;
}

// ---------- kernel 2: weight casts / gathers / zero pads (grid-stride) ----------
__global__ __launch_bounds__(256) void prep(
    const float* __restrict__ Wh0, const float* __restrict__ Wc0,
    const float* __restrict__ Wih, const float* __restrict__ Whh,
    const float* __restrict__ Wfc, const float* __restrict__ emb,
    const int* __restrict__ caps,
    short* __restrict__ Wcat, short* __restrict__ Wihe, short* __restrict__ Whhb,
    short* __restrict__ Wfcb, short* __restrict__ Xemb,
    unsigned short* __restrict__ Hall, unsigned short* __restrict__ App) {
  const long N1 = 3072L * 1536;            // Wcat: [Whi | Wlo | Whi] per row
  const long N2 = N1 + 2048L * 512;        // Wihe
  const long N3 = N2 + 2048L * 512;        // Whhb
  const long N4 = N3 + 10112L * 512;       // Wfcb (padded)
  const long N5 = N4 + 4096L * 512;        // Xemb (padded)
  const long N6 = N5 + 64L * 512;          // Hall pad rows
  const long N7 = N6 + 64L * 1536;         // App pad rows
  for (long idx = (long)blockIdx.x * 256 + threadIdx.x; idx < N7; idx += 2048L * 256) {
    if (idx < N1) {
      int j = (int)(idx / 1536);
      int kk = (int)(idx - (long)j * 1536);
      int k = kk & 511, seg = kk >> 9;
      const float* src = (j < 512) ? (Wh0 + (long)j * 512)
                       : (j < 1024) ? (Wc0 + (long)(j - 512) * 512)
                                    : (Wih + (long)(j - 1024) * 1024 + 512);
      float x = src[k];
      unsigned short hi = f2bf(x);
      Wcat[idx] = (seg == 1) ? (short)f2bf(x - bf2f(hi)) : (short)hi;
    } else if (idx < N2) {
      long e = idx - N1;
      Wihe[e] = (short)f2bf(Wih[(e >> 9) * 1024 + (e & 511)]);
    } else if (idx < N3) {
      long e = idx - N2;
      Whhb[e] = (short)f2bf(Whh[e]);
    } else if (idx < N4) {
      long e = idx - N3;
      long j = e >> 9;
      Wfcb[e] = (j < V_) ? (short)f2bf(Wfc[e]) : (short)0;
    } else if (idx < N5) {
      long e = idx - N4;
      int m = (int)(e >> 9), k = (int)(e & 511);
      short v = 0;
      if (m < B_ * TDEC) {
        int b = m / TDEC, t = m - b * TDEC;
        int tok = caps[b * 64 + t];
        v = (short)f2bf(emb[(long)tok * 512 + k]);
      }
      Xemb[e] = v;
    } else if (idx < N6) {
      long e = idx - N5;
      Hall[(long)B_ * TDEC * 512 + e] = 0;
    } else {
      long e = idx - N6;
      App[64L * 1536 + e] = 0;
    }
  }
}

// ---------- generic 128x128 bf16 MFMA GEMM, C = A(MxK) * B(NxK)^T ----------
// MODE 0: init GEMM (A'',Wcat,K=1536) -> h0f/c0f (x 1/196 + bias) + hbuf(bf16) + ENCC(+b_ih+b_hh)
// MODE 1: PG = Xemb @ Wihe^T (bf16 store)
// MODE 2: out = mask(Hall @ Wfcb^T + b_fc)
template <int MODE>
__global__ __launch_bounds__(256) void gemm128(
    const short* __restrict__ A, const short* __restrict__ Bm, int K,
    float* __restrict__ f0, float* __restrict__ f1, float* __restrict__ f2,
    unsigned short* __restrict__ sb,
    const float* __restrict__ b0, const float* __restrict__ b1,
    const float* __restrict__ b2, const float* __restrict__ b3,
    const int* __restrict__ caplen) {
  __shared__ short Al[4096], Bl[4096];
  const int tid = threadIdx.x, lane = tid & 63, w = tid >> 6;
  const int wr = w >> 1, wc = w & 1;
  const long m0 = (long)blockIdx.y * 128, n0 = (long)blockIdx.x * 128;
  f32x4 zz = {0.f, 0.f, 0.f, 0.f};
  f32x4 acc[4][4];
#pragma unroll
  for (int i = 0; i < 4; ++i)
#pragma unroll
    for (int j = 0; j < 4; ++j) acc[i][j] = zz;

  const int srow = tid >> 2, scol = (tid & 3) * 8;
  const short* Ag = A + (m0 + srow) * K + scol;
  const short* Bg = Bm + (n0 + srow) * K + scol;
  short* Alw = &Al[w * 512];
  short* Blw = &Bl[w * 512];
  const int la = (lane & 15) * 32 + (lane >> 4) * 8;

  for (int k0 = 0; k0 < K; k0 += 32) {
    __syncthreads();
    gl16(Ag + k0, Alw);
    gl16(Ag + (long)64 * K + k0, Alw + 2048);
    gl16(Bg + k0, Blw);
    gl16(Bg + (long)64 * K + k0, Blw + 2048);
    __syncthreads();
    bf16x8 af[4], bfr[4];
#pragma unroll
    for (int mi = 0; mi < 4; ++mi) af[mi] = *(const bf16x8*)&Al[(wr * 64 + mi * 16) * 32 + la];
#pragma unroll
    for (int ni = 0; ni < 4; ++ni) bfr[ni] = *(const bf16x8*)&Bl[(wc * 64 + ni * 16) * 32 + la];
#pragma unroll
    for (int mi = 0; mi < 4; ++mi)
#pragma unroll
      for (int ni = 0; ni < 4; ++ni)
        acc[mi][ni] = __builtin_amdgcn_mfma_f32_16x16x32_bf16(af[mi], bfr[ni], acc[mi][ni], 0, 0, 0);
  }

  if constexpr (MODE == 0) {
    if (wr == 1) return;  // rows 64..127 are padding
#pragma unroll
    for (int mi = 0; mi < 4; ++mi) {
#pragma unroll
      for (int ni = 0; ni < 4; ++ni) {
        int n = (int)n0 + wc * 64 + ni * 16 + (lane & 15);
#pragma unroll
        for (int reg = 0; reg < 4; ++reg) {
          int m = mi * 16 + (lane >> 4) * 4 + reg;
          float v = acc[mi][ni][reg];
          if (n < 512) {
            float r = v * (1.f / 196.f) + b0[n];
            f0[m * 512 + n] = r;
            sb[m * 512 + n] = f2bf(r);
          } else if (n < 1024) {
            int nn = n - 512;
            float r = v * (1.f / 196.f) + b1[nn];
            f1[m * 512 + nn] = r;
          } else {
            int nn = n - 1024;
            f2[m * 2048 + nn] = v + b2[nn] + b3[nn];
          }
        }
      }
    }
  }
  if constexpr (MODE == 1) {
#pragma unroll
    for (int mi = 0; mi < 4; ++mi) {
#pragma unroll
      for (int reg = 0; reg < 4; ++reg) {
        long m = m0 + wr * 64 + mi * 16 + (lane >> 4) * 4 + reg;
#pragma unroll
        for (int ni = 0; ni < 4; ++ni) {
          int n = (int)n0 + wc * 64 + ni * 16 + (lane & 15);
          sb[m * 2048 + n] = f2bf(acc[mi][ni][reg]);
        }
      }
    }
  }
  if constexpr (MODE == 2) {
#pragma unroll
    for (int mi = 0; mi < 4; ++mi) {
#pragma unroll
      for (int reg = 0; reg < 4; ++reg) {
        long m = m0 + wr * 64 + mi * 16 + (lane >> 4) * 4 + reg;
        if (m < (long)B_ * TDEC) {
          int b = (int)(m / TDEC);
          int tt = (int)(m - (long)b * TDEC);
          bool act = tt < (caplen[b] - 1);
          float* orow = f0 + m * V_;
#pragma unroll
          for (int ni = 0; ni < 4; ++ni) {
            int n = (int)n0 + wc * 64 + ni * 16 + (lane & 15);
            if (n < V_) orow[n] = act ? (acc[mi][ni][reg] + b0[n]) : 0.f;
          }
        }
      }
    }
  }
}

// ---------- persistent LSTM recurrence ----------
// 64 WGs; WG wg owns hidden dims [wg*8, wg*8+8) across all 4 gates (32 W_hh rows, LDS, swizzled).
// h broadcast via double-buffered global bf16 hbuf; one device-scope grid barrier per step.
__global__ __launch_bounds__(256, 1) void lstm_rec(
    const short* __restrict__ Whhb, const float* __restrict__ ENCC,
    const short* __restrict__ PG, const float* __restrict__ h0f,
    const float* __restrict__ c0f, const int* __restrict__ caplen,
    unsigned short* __restrict__ hbuf, unsigned short* __restrict__ Hall,
    int* __restrict__ bar) {
  __shared__ short Wl[32 * 512];
  __shared__ float encc_l[64 * 33];
  __shared__ float gates_l[64 * 33];
  const int tid = threadIdx.x, lane = tid & 63, w = tid >> 6;
  const int wg = blockIdx.x, d0 = wg * 8;

  // load W_hh slice (rows r = g*8+dl  <->  j = g*512 + d0 + dl), XOR-swizzled vs bank conflicts
  for (int it = tid; it < 2048; it += 256) {
    int r = it >> 6, c8 = it & 63;
    int j = ((r >> 3) << 9) + d0 + (r & 7);
    bf16x8 v = *(const bf16x8*)(Whhb + (long)j * 512 + c8 * 8);
    *(bf16x8*)&Wl[r * 512 + ((c8 * 8) ^ ((r & 7) << 3))] = v;
  }
  for (int it = tid; it < 64 * 32; it += 256) {
    int b = it >> 5, r = it & 31;
    encc_l[b * 33 + r] = ENCC[b * 2048 + ((r >> 3) << 9) + d0 + (r & 7)];
  }
  const int bp = tid >> 2, dl0 = (tid & 3) * 2;
  const int declen = caplen[bp] - 1;
  float c_r[2], h_r[2];
  c_r[0] = c0f[bp * 512 + d0 + dl0];
  c_r[1] = c0f[bp * 512 + d0 + dl0 + 1];
  h_r[0] = h0f[bp * 512 + d0 + dl0];
  h_r[1] = h0f[bp * 512 + d0 + dl0 + 1];
  __syncthreads();

  const int arow = 16 * w + (lane & 15);
  const int kgo = (lane >> 4) * 8;
  const int r0 = lane & 15, r1 = 16 + (lane & 15);

  for (int t = 0; t < TDEC; ++t) {
    const unsigned short* hsrc = hbuf + (t & 1) * 32768;
    f32x4 acc0 = {0.f, 0.f, 0.f, 0.f}, acc1 = {0.f, 0.f, 0.f, 0.f};
#pragma unroll
    for (int k0 = 0; k0 < 512; k0 += 32) {
      bf16x8 a = *(const bf16x8*)(hsrc + arow * 512 + k0 + kgo);
      bf16x8 bb0 = *(const bf16x8*)&Wl[r0 * 512 + ((k0 + kgo) ^ ((r0 & 7) << 3))];
      bf16x8 bb1 = *(const bf16x8*)&Wl[r1 * 512 + ((k0 + kgo) ^ ((r1 & 7) << 3))];
      acc0 = __builtin_amdgcn_mfma_f32_16x16x32_bf16(a, bb0, acc0, 0, 0, 0);
      acc1 = __builtin_amdgcn_mfma_f32_16x16x32_bf16(a, bb1, acc1, 0, 0, 0);
    }
#pragma unroll
    for (int reg = 0; reg < 4; ++reg) {
      int b = 16 * w + (lane >> 4) * 4 + reg;
      gates_l[b * 33 + (lane & 15)] = acc0[reg];
      gates_l[b * 33 + 16 + (lane & 15)] = acc1[reg];
    }
    __syncthreads();
    // pointwise LSTM for (bp, d0+dl0) and (bp, d0+dl0+1)
    {
      const long pgbase = ((long)(bp * TDEC + t)) * 2048 + d0 + dl0;
      unsigned pgi = *(const unsigned*)(PG + pgbase);
      unsigned pgf = *(const unsigned*)(PG + pgbase + 512);
      unsigned pgg = *(const unsigned*)(PG + pgbase + 1024);
      unsigned pgo = *(const unsigned*)(PG + pgbase + 1536);
      bool act = t < declen;
      unsigned short h2p[2], hnp[2];
#pragma unroll
      for (int qq = 0; qq < 2; ++qq) {
        int q = dl0 + qq;
        float ii = gates_l[bp * 33 + q] + encc_l[bp * 33 + q] +
                   bf2f((unsigned short)(qq ? (pgi >> 16) : (pgi & 0xffff)));
        float ff = gates_l[bp * 33 + 8 + q] + encc_l[bp * 33 + 8 + q] +
                   bf2f((unsigned short)(qq ? (pgf >> 16) : (pgf & 0xffff)));
        float gg = gates_l[bp * 33 + 16 + q] + encc_l[bp * 33 + 16 + q] +
                   bf2f((unsigned short)(qq ? (pgg >> 16) : (pgg & 0xffff)));
        float oo = gates_l[bp * 33 + 24 + q] + encc_l[bp * 33 + 24 + q] +
                   bf2f((unsigned short)(qq ? (pgo >> 16) : (pgo & 0xffff)));
        ii = sigm(ii); ff = sigm(ff); oo = sigm(oo); gg = tanhf(gg);
        float cn = ff * c_r[qq] + ii * gg;
        float hn = oo * tanhf(cn);
        if (act) { c_r[qq] = cn; h_r[qq] = hn; }
        h2p[qq] = f2bf(h_r[qq]);
        hnp[qq] = f2bf(hn);
      }
      *(unsigned*)&hbuf[((t + 1) & 1) * 32768 + bp * 512 + d0 + dl0] =
          (unsigned)h2p[0] | ((unsigned)h2p[1] << 16);
      *(unsigned*)&Hall[((long)(bp * TDEC + t)) * 512 + d0 + dl0] =
          (unsigned)hnp[0] | ((unsigned)hnp[1] << 16);
    }
    if (t < TDEC - 1) {
      __syncthreads();
      if (tid == 0) {
        __hip_atomic_fetch_add(bar, 1, __ATOMIC_RELEASE, __HIP_MEMORY_SCOPE_AGENT);
        int target = NWG * (t + 1);
        while (__hip_atomic_load(bar, __ATOMIC_ACQUIRE, __HIP_MEMORY_SCOPE_AGENT) < target)
          __builtin_amdgcn_s_sleep(2);
      }
      __syncthreads();
    }
  }
}

// ---------- host ----------
extern "C" void kernel_launch(void* const* d_in, const int* in_sizes, int n_in,
                              void* d_out, int out_size, void* d_ws, size_t ws_size,
                              hipStream_t stream) {
  const float* enc = (const float*)d_in[0];
  const int* caps = (const int*)d_in[1];
  const int* clen = (const int*)d_in[2];
  const float* emb = (const float*)d_in[3];
  const float* Wih = (const float*)d_in[4];
  const float* bih = (const float*)d_in[5];
  const float* Whh = (const float*)d_in[6];
  const float* bhh = (const float*)d_in[7];
  const float* Wh0 = (const float*)d_in[8];
  const float* bh0 = (const float*)d_in[9];
  const float* Wc0 = (const float*)d_in[10];
  const float* bc0 = (const float*)d_in[11];
  const float* Wfc = (const float*)d_in[12];
  const float* bfc = (const float*)d_in[13];
  float* out = (float*)d_out;

  char* ws = (char*)d_ws;
  size_t off = 0;
  auto alloc = [&](size_t bytes) {
    void* p = ws + off;
    off = (off + bytes + 255) & ~(size_t)255;
    return p;
  };
  int* bar = (int*)alloc(256);
  unsigned short* App = (unsigned short*)alloc(128L * 1536 * 2);
  short* Wcat = (short*)alloc(3072L * 1536 * 2);
  short* Wihe = (short*)alloc(2048L * 512 * 2);
  short* Whhb = (short*)alloc(2048L * 512 * 2);
  short* Wfcb = (short*)alloc(10112L * 512 * 2);
  short* Xemb = (short*)alloc(4096L * 512 * 2);
  short* PGb = (short*)alloc(4096L * 2048 * 2);
  float* ENCCb = (float*)alloc(64L * 2048 * 4);
  float* h0f = (float*)alloc(64L * 512 * 4);
  float* c0f = (float*)alloc(64L * 512 * 4);
  unsigned short* hbuf = (unsigned short*)alloc(2L * 64 * 512 * 2);
  unsigned short* Hall = (unsigned short*)alloc(4096L * 512 * 2);
  (void)ws_size; (void)in_sizes; (void)n_in; (void)out_size;

  hipMemsetAsync(bar, 0, 256, stream);
  enc_reduce<<<dim3(64, 2), 256, 0, stream>>>(enc, App);
  prep<<<2048, 256, 0, stream>>>(Wh0, Wc0, Wih, Whh, Wfc, emb, caps, Wcat, Wihe, Whhb,
                                 Wfcb, Xemb, Hall, App);
  gemm128<0><<<dim3(24, 1), 256, 0, stream>>>((const short*)App, Wcat, 1536, h0f, c0f,
                                              ENCCb, hbuf, bh0, bc0, bih, bhh, nullptr);
  gemm128<1><<<dim3(16, 32), 256, 0, stream>>>(Xemb, Wihe, 512, nullptr, nullptr, nullptr,
                                               (unsigned short*)PGb, nullptr, nullptr,
                                               nullptr, nullptr, nullptr);
  lstm_rec<<<dim3(NWG), 256, 0, stream>>>(Whhb, ENCCb, PGb, h0f, c0f, clen, hbuf, Hall, bar);
  gemm128<2><<<dim3(79, 32), 256, 0, stream>>>((const short*)Hall, Wfcb, 512, out, nullptr,
                                               nullptr, nullptr, bfc, nullptr, nullptr,
                                               nullptr, clen);
}

// Round 2
// 745.509 us; speedup vs baseline: 1.0062x; 1.0062x over previous
//
#include <hip/hip_runtime.h>

// ---------- small helpers ----------
typedef __attribute__((ext_vector_type(8))) short bf16x8;
typedef __attribute__((ext_vector_type(4))) float f32x4;
typedef __attribute__((ext_vector_type(2))) float f32x2;

__device__ __forceinline__ unsigned short f2bf(float x) {
  union { float f; unsigned u; } v; v.f = x;
  unsigned r = v.u + 0x7fffu + ((v.u >> 16) & 1u);
  return (unsigned short)(r >> 16);
}
__device__ __forceinline__ float bf2f(unsigned short s) {
  union { unsigned u; float f; } v; v.u = ((unsigned)s) << 16;
  return v.f;
}
__device__ __forceinline__ float sigm(float x) { return 1.f / (1.f + __expf(-x)); }
__device__ __forceinline__ float tanh_fast(float x) { return 2.f * sigm(2.f * x) - 1.f; }

typedef const __attribute__((address_space(1))) void gvoid_t;
typedef __attribute__((address_space(3))) void lvoid_t;
__device__ __forceinline__ void gl16(const void* g, void* l) {
  __builtin_amdgcn_global_load_lds((gvoid_t*)g, (lvoid_t*)l, 16, 0, 0);
}

#define B_ 64
#define TDEC 63
#define D_ 512
#define V_ 10000
#define NWG 32

// ---------- kernel 1: encoder sum + bf16x3 A'' build ----------
__global__ __launch_bounds__(256) void enc_reduce(const float* __restrict__ enc,
                                                  unsigned short* __restrict__ App) {
  int b = blockIdx.x;
  int d = blockIdx.y * 256 + threadIdx.x;
  const float* p = enc + (long)b * 196 * 512 + d;
  float s = 0.f;
#pragma unroll 4
  for (int i = 0; i < 196; ++i) s += p[(long)i * 512];
  unsigned short hi = f2bf(s);
  unsigned short lo = f2bf(s - bf2f(hi));
  App[b * 1536 + d] = hi;
  App[b * 1536 + 512 + d] = hi;
  App[b * 1536 + 1024 + d] = lo;
}

// ---------- kernel 2: weight casts / gathers / zero pads (grid-stride) ----------
__global__ __launch_bounds__(256) void prep(
    const float* __restrict__ Wh0, const float* __restrict__ Wc0,
    const float* __restrict__ Wih, const float* __restrict__ Whh,
    const float* __restrict__ Wfc, const float* __restrict__ emb,
    const int* __restrict__ caps,
    short* __restrict__ Wcat, short* __restrict__ Wihe, short* __restrict__ Whhb,
    short* __restrict__ Wfcb, short* __restrict__ Xemb,
    unsigned short* __restrict__ Hall, unsigned short* __restrict__ App) {
  const long N1 = 3072L * 1536;            // Wcat
  const long N2 = N1 + 2048L * 512;        // Wihe
  const long N3 = N2 + 2048L * 512;        // Whhb
  const long N4 = N3 + 10112L * 512;       // Wfcb (padded)
  const long N5 = N4 + 4096L * 512;        // Xemb (padded)
  const long N6 = N5 + 64L * 512;          // Hall pad rows
  const long N7 = N6 + 64L * 1536;         // App pad rows
  for (long idx = (long)blockIdx.x * 256 + threadIdx.x; idx < N7; idx += 2048L * 256) {
    if (idx < N1) {
      int j = (int)(idx / 1536);
      int kk = (int)(idx - (long)j * 1536);
      int k = kk & 511, seg = kk >> 9;
      const float* src = (j < 512) ? (Wh0 + (long)j * 512)
                       : (j < 1024) ? (Wc0 + (long)(j - 512) * 512)
                                    : (Wih + (long)(j - 1024) * 1024 + 512);
      float x = src[k];
      unsigned short hi = f2bf(x);
      Wcat[idx] = (seg == 1) ? (short)f2bf(x - bf2f(hi)) : (short)hi;
    } else if (idx < N2) {
      long e = idx - N1;
      Wihe[e] = (short)f2bf(Wih[(e >> 9) * 1024 + (e & 511)]);
    } else if (idx < N3) {
      long e = idx - N2;
      Whhb[e] = (short)f2bf(Whh[e]);
    } else if (idx < N4) {
      long e = idx - N3;
      long j = e >> 9;
      Wfcb[e] = (j < V_) ? (short)f2bf(Wfc[e]) : (short)0;
    } else if (idx < N5) {
      long e = idx - N4;
      int m = (int)(e >> 9), k = (int)(e & 511);
      short v = 0;
      if (m < B_ * TDEC) {
        int b = m / TDEC, t = m - b * TDEC;
        int tok = caps[b * 64 + t];
        v = (short)f2bf(emb[(long)tok * 512 + k]);
      }
      Xemb[e] = v;
    } else if (idx < N6) {
      long e = idx - N5;
      Hall[(long)B_ * TDEC * 512 + e] = 0;
    } else {
      long e = idx - N6;
      App[64L * 1536 + e] = 0;
    }
  }
}

// ---------- generic 128x128 bf16 MFMA GEMM, C = A(MxK) * B(NxK)^T ----------
// MODE 0: init GEMM -> h0f/c0f (+bias, /196) + hbuf(bf16) + ENCCT[row][b](+b_ih+b_hh)
// MODE 1: PGT[t][row][b] = bf16(Xemb @ Wihe^T)
// MODE 2: out = mask(Hall @ Wfcb^T + b_fc)
template <int MODE>
__global__ __launch_bounds__(256) void gemm128(
    const short* __restrict__ A, const short* __restrict__ Bm, int K,
    float* __restrict__ f0, float* __restrict__ f1, float* __restrict__ f2,
    unsigned short* __restrict__ sb,
    const float* __restrict__ b0, const float* __restrict__ b1,
    const float* __restrict__ b2, const float* __restrict__ b3,
    const int* __restrict__ caplen) {
  __shared__ short Al[4096], Bl[4096];
  const int tid = threadIdx.x, lane = tid & 63, w = tid >> 6;
  const int wr = w >> 1, wc = w & 1;
  const long m0 = (long)blockIdx.y * 128, n0 = (long)blockIdx.x * 128;
  f32x4 zz = {0.f, 0.f, 0.f, 0.f};
  f32x4 acc[4][4];
#pragma unroll
  for (int i = 0; i < 4; ++i)
#pragma unroll
    for (int j = 0; j < 4; ++j) acc[i][j] = zz;

  const int srow = tid >> 2, scol = (tid & 3) * 8;
  const short* Ag = A + (m0 + srow) * K + scol;
  const short* Bg = Bm + (n0 + srow) * K + scol;
  short* Alw = &Al[w * 512];
  short* Blw = &Bl[w * 512];
  const int la = (lane & 15) * 32 + (lane >> 4) * 8;

  for (int k0 = 0; k0 < K; k0 += 32) {
    __syncthreads();
    gl16(Ag + k0, Alw);
    gl16(Ag + (long)64 * K + k0, Alw + 2048);
    gl16(Bg + k0, Blw);
    gl16(Bg + (long)64 * K + k0, Blw + 2048);
    __syncthreads();
    bf16x8 af[4], bfr[4];
#pragma unroll
    for (int mi = 0; mi < 4; ++mi) af[mi] = *(const bf16x8*)&Al[(wr * 64 + mi * 16) * 32 + la];
#pragma unroll
    for (int ni = 0; ni < 4; ++ni) bfr[ni] = *(const bf16x8*)&Bl[(wc * 64 + ni * 16) * 32 + la];
#pragma unroll
    for (int mi = 0; mi < 4; ++mi)
#pragma unroll
      for (int ni = 0; ni < 4; ++ni)
        acc[mi][ni] = __builtin_amdgcn_mfma_f32_16x16x32_bf16(af[mi], bfr[ni], acc[mi][ni], 0, 0, 0);
  }

  if constexpr (MODE == 0) {
    if (wr == 1) return;
#pragma unroll
    for (int mi = 0; mi < 4; ++mi) {
#pragma unroll
      for (int ni = 0; ni < 4; ++ni) {
        int n = (int)n0 + wc * 64 + ni * 16 + (lane & 15);
#pragma unroll
        for (int reg = 0; reg < 4; ++reg) {
          int m = mi * 16 + (lane >> 4) * 4 + reg;
          float v = acc[mi][ni][reg];
          if (n < 512) {
            float r = v * (1.f / 196.f) + b0[n];
            f0[m * 512 + n] = r;
            sb[m * 512 + n] = f2bf(r);
          } else if (n < 1024) {
            int nn = n - 512;
            float r = v * (1.f / 196.f) + b1[nn];
            f1[m * 512 + nn] = r;
          } else {
            int nn = n - 1024;
            f2[(long)nn * 64 + m] = v + b2[nn] + b3[nn];  // ENCCT[row][b]
          }
        }
      }
    }
  }
  if constexpr (MODE == 1) {
#pragma unroll
    for (int mi = 0; mi < 4; ++mi) {
#pragma unroll
      for (int reg = 0; reg < 4; ++reg) {
        long m = m0 + wr * 64 + mi * 16 + (lane >> 4) * 4 + reg;
        if (m < (long)B_ * TDEC) {
          int b = (int)(m / TDEC);
          int t = (int)(m - (long)b * TDEC);
          unsigned short* dst = sb + (long)t * 2048 * 64;
#pragma unroll
          for (int ni = 0; ni < 4; ++ni) {
            int n = (int)n0 + wc * 64 + ni * 16 + (lane & 15);
            dst[(long)n * 64 + b] = f2bf(acc[mi][ni][reg]);  // PGT[t][row][b]
          }
        }
      }
    }
  }
  if constexpr (MODE == 2) {
#pragma unroll
    for (int mi = 0; mi < 4; ++mi) {
#pragma unroll
      for (int reg = 0; reg < 4; ++reg) {
        long m = m0 + wr * 64 + mi * 16 + (lane >> 4) * 4 + reg;
        if (m < (long)B_ * TDEC) {
          int b = (int)(m / TDEC);
          int tt = (int)(m - (long)b * TDEC);
          bool act = tt < (caplen[b] - 1);
          float* orow = f0 + m * V_;
#pragma unroll
          for (int ni = 0; ni < 4; ++ni) {
            int n = (int)n0 + wc * 64 + ni * 16 + (lane & 15);
            if (n < V_) orow[n] = act ? (acc[mi][ni][reg] + b0[n]) : 0.f;
          }
        }
      }
    }
  }
}

// ---------- persistent LSTM recurrence ----------
// 32 WGs x 512 thr. WG wg owns dims [wg*16, wg*16+16) x 4 gates = 64 W_hh rows in LDS.
// Wave w: br=w>>1 (16 batches), rc=w&1 (8 dims). Rows r' = rc*32 + g*8 + dl.
// Gates exchanged via shfl_xor(8); c/h state in registers; relaxed-poll grid barrier.
__global__ __launch_bounds__(512, 1) void lstm_rec(
    const short* __restrict__ Whhb, const float* __restrict__ ENCCT,
    const unsigned short* __restrict__ PGT, const float* __restrict__ h0f,
    const float* __restrict__ c0f, const int* __restrict__ caplen,
    unsigned short* __restrict__ hbuf, unsigned short* __restrict__ Hall,
    int* __restrict__ bar) {
  __shared__ short Wl[64 * 512];
  const int tid = threadIdx.x, lane = tid & 63, w = tid >> 6;
  const int wg = blockIdx.x, d0 = wg * 16;
  const int br = w >> 1, rc = w & 1;

  // stage W_hh slice, swizzled: row r' <-> Whh row j = g*512 + d0 + rcc*8 + dl
  for (int it = tid; it < 4096; it += 512) {
    int r = it >> 6, c8 = it & 63;
    int g = (r >> 3) & 3, rcc = r >> 5, dl_ = r & 7;
    int j = g * 512 + d0 + rcc * 8 + dl_;
    bf16x8 v = *(const bf16x8*)(Whhb + (long)j * 512 + c8 * 8);
    *(bf16x8*)&Wl[r * 512 + ((c8 * 8) ^ ((r & 7) << 3))] = v;
  }

  const int q = (lane >> 4) & 3, bit3 = (lane >> 3) & 1, dl = lane & 7;
  const int d = d0 + rc * 8 + dl;             // this lane's hidden dim
  const int b0 = br * 16 + q * 4 + 2 * bit3;  // this lane's 2 batches
  const int ji = d, jf = 512 + d, jg = 1024 + d, jo = 1536 + d;

  f32x2 ei = *(const f32x2*)(ENCCT + (long)ji * 64 + b0);
  f32x2 ef = *(const f32x2*)(ENCCT + (long)jf * 64 + b0);
  f32x2 eg = *(const f32x2*)(ENCCT + (long)jg * 64 + b0);
  f32x2 eo = *(const f32x2*)(ENCCT + (long)jo * 64 + b0);
  float c_r[2] = {c0f[b0 * 512 + d], c0f[(b0 + 1) * 512 + d]};
  float h_r[2] = {h0f[b0 * 512 + d], h0f[(b0 + 1) * 512 + d]};
  int dlen0 = caplen[b0] - 1, dlen1 = caplen[b0 + 1] - 1;
  __syncthreads();

  const int arow = br * 16 + (lane & 15);
  const int kgo = (lane >> 4) * 8;
  const int r0 = rc * 32 + (lane & 15), r1 = rc * 32 + 16 + (lane & 15);
  const int sw0 = (r0 & 7) << 3, sw1 = (r1 & 7) << 3;

  for (int t = 0; t < TDEC; ++t) {
    const unsigned short* hsrc = hbuf + (t & 1) * 32768;
    // preload all A fragments (one memory round-trip)
    bf16x8 av[16];
#pragma unroll
    for (int kk = 0; kk < 16; ++kk)
      av[kk] = *(const bf16x8*)(hsrc + arow * 512 + kk * 32 + kgo);
    f32x4 a0 = {0.f, 0.f, 0.f, 0.f}, a1 = {0.f, 0.f, 0.f, 0.f};
#pragma unroll
    for (int kk = 0; kk < 16; ++kk) {
      int k = kk * 32 + kgo;
      bf16x8 b0v = *(const bf16x8*)&Wl[r0 * 512 + (k ^ sw0)];
      bf16x8 b1v = *(const bf16x8*)&Wl[r1 * 512 + (k ^ sw1)];
      a0 = __builtin_amdgcn_mfma_f32_16x16x32_bf16(av[kk], b0v, a0, 0, 0, 0);
      a1 = __builtin_amdgcn_mfma_f32_16x16x32_bf16(av[kk], b1v, a1, 0, 0, 0);
    }
    // own/send selects + cross-lane exchange (pair lanes l <-> l^8)
    float own00 = bit3 ? a0[2] : a0[0], own01 = bit3 ? a0[3] : a0[1];
    float snd00 = bit3 ? a0[0] : a0[2], snd01 = bit3 ? a0[1] : a0[3];
    float own10 = bit3 ? a1[2] : a1[0], own11 = bit3 ? a1[3] : a1[1];
    float snd10 = bit3 ? a1[0] : a1[2], snd11 = bit3 ? a1[1] : a1[3];
    float rcv00 = __shfl_xor(snd00, 8, 64), rcv01 = __shfl_xor(snd01, 8, 64);
    float rcv10 = __shfl_xor(snd10, 8, 64), rcv11 = __shfl_xor(snd11, 8, 64);
    float iv[2], fv[2], gv[2], ov[2];
    iv[0] = bit3 ? rcv00 : own00; iv[1] = bit3 ? rcv01 : own01;
    fv[0] = bit3 ? own00 : rcv00; fv[1] = bit3 ? own01 : rcv01;
    gv[0] = bit3 ? rcv10 : own10; gv[1] = bit3 ? rcv11 : own11;
    ov[0] = bit3 ? own10 : rcv10; ov[1] = bit3 ? own11 : rcv11;

    const unsigned short* pgt = PGT + (long)t * 2048 * 64;
    ushort2 pi = *(const ushort2*)(pgt + (long)ji * 64 + b0);
    ushort2 pf = *(const ushort2*)(pgt + (long)jf * 64 + b0);
    ushort2 pg = *(const ushort2*)(pgt + (long)jg * 64 + b0);
    ushort2 po = *(const ushort2*)(pgt + (long)jo * 64 + b0);

    unsigned short* hdst = hbuf + ((t + 1) & 1) * 32768;
#pragma unroll
    for (int r = 0; r < 2; ++r) {
      float ii = iv[r] + ei[r] + bf2f(r ? pi.y : pi.x);
      float ff = fv[r] + ef[r] + bf2f(r ? pf.y : pf.x);
      float gg = gv[r] + eg[r] + bf2f(r ? pg.y : pg.x);
      float oo = ov[r] + eo[r] + bf2f(r ? po.y : po.x);
      ii = sigm(ii); ff = sigm(ff); oo = sigm(oo); gg = tanh_fast(gg);
      float cn = ff * c_r[r] + ii * gg;
      float hn = oo * tanh_fast(cn);
      bool act = t < (r ? dlen1 : dlen0);
      if (act) { c_r[r] = cn; h_r[r] = hn; }
      hdst[(b0 + r) * 512 + d] = f2bf(h_r[r]);
      Hall[((long)(b0 + r) * TDEC + t) * 512 + d] = f2bf(hn);
    }

    if (t < TDEC - 1) {
      __syncthreads();
      if (tid == 0) {
        __hip_atomic_fetch_add(bar, 1, __ATOMIC_RELEASE, __HIP_MEMORY_SCOPE_AGENT);
        int target = NWG * (t + 1);
        int spins = 0;
        while (true) {
          int v = ((++spins) & 63)
                      ? __hip_atomic_load(bar, __ATOMIC_RELAXED, __HIP_MEMORY_SCOPE_AGENT)
                      : __hip_atomic_load(bar, __ATOMIC_ACQUIRE, __HIP_MEMORY_SCOPE_AGENT);
          if (v >= target) break;
          __builtin_amdgcn_s_sleep(1);
        }
        (void)__hip_atomic_load(bar, __ATOMIC_ACQUIRE, __HIP_MEMORY_SCOPE_AGENT);
      }
      __syncthreads();
    }
  }
}

// ---------- host ----------
extern "C" void kernel_launch(void* const* d_in, const int* in_sizes, int n_in,
                              void* d_out, int out_size, void* d_ws, size_t ws_size,
                              hipStream_t stream) {
  const float* enc = (const float*)d_in[0];
  const int* caps = (const int*)d_in[1];
  const int* clen = (const int*)d_in[2];
  const float* emb = (const float*)d_in[3];
  const float* Wih = (const float*)d_in[4];
  const float* bih = (const float*)d_in[5];
  const float* Whh = (const float*)d_in[6];
  const float* bhh = (const float*)d_in[7];
  const float* Wh0 = (const float*)d_in[8];
  const float* bh0 = (const float*)d_in[9];
  const float* Wc0 = (const float*)d_in[10];
  const float* bc0 = (const float*)d_in[11];
  const float* Wfc = (const float*)d_in[12];
  const float* bfc = (const float*)d_in[13];
  float* out = (float*)d_out;

  char* ws = (char*)d_ws;
  size_t off = 0;
  auto alloc = [&](size_t bytes) {
    void* p = ws + off;
    off = (off + bytes + 255) & ~(size_t)255;
    return p;
  };
  int* bar = (int*)alloc(256);
  unsigned short* App = (unsigned short*)alloc(128L * 1536 * 2);
  short* Wcat = (short*)alloc(3072L * 1536 * 2);
  short* Wihe = (short*)alloc(2048L * 512 * 2);
  short* Whhb = (short*)alloc(2048L * 512 * 2);
  short* Wfcb = (short*)alloc(10112L * 512 * 2);
  short* Xemb = (short*)alloc(4096L * 512 * 2);
  unsigned short* PGT = (unsigned short*)alloc(63L * 2048 * 64 * 2);
  float* ENCCT = (float*)alloc(2048L * 64 * 4);
  float* h0f = (float*)alloc(64L * 512 * 4);
  float* c0f = (float*)alloc(64L * 512 * 4);
  unsigned short* hbuf = (unsigned short*)alloc(2L * 64 * 512 * 2);
  unsigned short* Hall = (unsigned short*)alloc(4096L * 512 * 2);
  (void)ws_size; (void)in_sizes; (void)n_in; (void)out_size;

  hipMemsetAsync(bar, 0, 256, stream);
  enc_reduce<<<dim3(64, 2), 256, 0, stream>>>(enc, App);
  prep<<<2048, 256, 0, stream>>>(Wh0, Wc0, Wih, Whh, Wfc, emb, caps, Wcat, Wihe, Whhb,
                                 Wfcb, Xemb, Hall, App);
  gemm128<0><<<dim3(24, 1), 256, 0, stream>>>((const short*)App, Wcat, 1536, h0f, c0f,
                                              ENCCT, hbuf, bh0, bc0, bih, bhh, nullptr);
  gemm128<1><<<dim3(16, 32), 256, 0, stream>>>(Xemb, Wihe, 512, nullptr, nullptr, nullptr,
                                               PGT, nullptr, nullptr, nullptr, nullptr,
                                               nullptr);
  lstm_rec<<<dim3(NWG), 512, 0, stream>>>(Whhb, ENCCT, PGT, h0f, c0f, clen, hbuf, Hall, bar);
  gemm128<2><<<dim3(79, 32), 256, 0, stream>>>((const short*)Hall, Wfcb, 512, out, nullptr,
                                               nullptr, nullptr, bfc, nullptr, nullptr,
                                               nullptr, clen);
}

// Round 3
// 707.949 us; speedup vs baseline: 1.0596x; 1.0531x over previous
//
#include <hip/hip_runtime.h>

// ---------- small helpers ----------
typedef __attribute__((ext_vector_type(8))) short bf16x8;
typedef __attribute__((ext_vector_type(4))) float f32x4;
typedef __attribute__((ext_vector_type(2))) float f32x2;

__device__ __forceinline__ unsigned short f2bf(float x) {
  union { float f; unsigned u; } v; v.f = x;
  unsigned r = v.u + 0x7fffu + ((v.u >> 16) & 1u);
  return (unsigned short)(r >> 16);
}
__device__ __forceinline__ float bf2f(unsigned short s) {
  union { unsigned u; float f; } v; v.u = ((unsigned)s) << 16;
  return v.f;
}
__device__ __forceinline__ float sigm(float x) { return 1.f / (1.f + __expf(-x)); }
__device__ __forceinline__ float tanh_fast(float x) { return 2.f * sigm(2.f * x) - 1.f; }

typedef const __attribute__((address_space(1))) void gvoid_t;
typedef __attribute__((address_space(3))) void lvoid_t;
__device__ __forceinline__ void gl16(const void* g, void* l) {
  __builtin_amdgcn_global_load_lds((gvoid_t*)g, (lvoid_t*)l, 16, 0, 0);
}

#define B_ 64
#define TDEC 63
#define D_ 512
#define V_ 10000
#define NWG 32

// ---------- kernel 1: encoder sum + bf16x3 A'' build ----------
__global__ __launch_bounds__(256) void enc_reduce(const float* __restrict__ enc,
                                                  unsigned short* __restrict__ App) {
  int b = blockIdx.x;
  int d = blockIdx.y * 256 + threadIdx.x;
  const float* p = enc + (long)b * 196 * 512 + d;
  float s = 0.f;
#pragma unroll 4
  for (int i = 0; i < 196; ++i) s += p[(long)i * 512];
  unsigned short hi = f2bf(s);
  unsigned short lo = f2bf(s - bf2f(hi));
  App[b * 1536 + d] = hi;
  App[b * 1536 + 512 + d] = hi;
  App[b * 1536 + 1024 + d] = lo;
}

// ---------- kernel 2: weight casts / gathers / zero pads (grid-stride) ----------
__global__ __launch_bounds__(256) void prep(
    const float* __restrict__ Wh0, const float* __restrict__ Wc0,
    const float* __restrict__ Wih, const float* __restrict__ Whh,
    const float* __restrict__ Wfc, const float* __restrict__ emb,
    const int* __restrict__ caps,
    short* __restrict__ Wcat, short* __restrict__ Wihe, short* __restrict__ Whhb,
    short* __restrict__ Wfcb, short* __restrict__ Xemb,
    unsigned short* __restrict__ Hall, unsigned short* __restrict__ App) {
  const long N1 = 3072L * 1536;            // Wcat
  const long N2 = N1 + 2048L * 512;        // Wihe
  const long N3 = N2 + 2048L * 512;        // Whhb
  const long N4 = N3 + 10112L * 512;       // Wfcb (padded)
  const long N5 = N4 + 4096L * 512;        // Xemb (padded)
  const long N6 = N5 + 64L * 512;          // Hall pad rows
  const long N7 = N6 + 64L * 1536;         // App pad rows
  for (long idx = (long)blockIdx.x * 256 + threadIdx.x; idx < N7; idx += 2048L * 256) {
    if (idx < N1) {
      int j = (int)(idx / 1536);
      int kk = (int)(idx - (long)j * 1536);
      int k = kk & 511, seg = kk >> 9;
      const float* src = (j < 512) ? (Wh0 + (long)j * 512)
                       : (j < 1024) ? (Wc0 + (long)(j - 512) * 512)
                                    : (Wih + (long)(j - 1024) * 1024 + 512);
      float x = src[k];
      unsigned short hi = f2bf(x);
      Wcat[idx] = (seg == 1) ? (short)f2bf(x - bf2f(hi)) : (short)hi;
    } else if (idx < N2) {
      long e = idx - N1;
      Wihe[e] = (short)f2bf(Wih[(e >> 9) * 1024 + (e & 511)]);
    } else if (idx < N3) {
      long e = idx - N2;
      Whhb[e] = (short)f2bf(Whh[e]);
    } else if (idx < N4) {
      long e = idx - N3;
      long j = e >> 9;
      Wfcb[e] = (j < V_) ? (short)f2bf(Wfc[e]) : (short)0;
    } else if (idx < N5) {
      long e = idx - N4;
      int m = (int)(e >> 9), k = (int)(e & 511);
      short v = 0;
      if (m < B_ * TDEC) {
        int b = m / TDEC, t = m - b * TDEC;
        int tok = caps[b * 64 + t];
        v = (short)f2bf(emb[(long)tok * 512 + k]);
      }
      Xemb[e] = v;
    } else if (idx < N6) {
      long e = idx - N5;
      Hall[(long)B_ * TDEC * 512 + e] = 0;
    } else {
      long e = idx - N6;
      App[64L * 1536 + e] = 0;
    }
  }
}

// ---------- generic 128x128 bf16 MFMA GEMM, C = A(MxK) * B(NxK)^T ----------
template <int MODE>
__global__ __launch_bounds__(256) void gemm128(
    const short* __restrict__ A, const short* __restrict__ Bm, int K,
    float* __restrict__ f0, float* __restrict__ f1, float* __restrict__ f2,
    unsigned short* __restrict__ sb,
    const float* __restrict__ b0, const float* __restrict__ b1,
    const float* __restrict__ b2, const float* __restrict__ b3,
    const int* __restrict__ caplen) {
  __shared__ short Al[4096], Bl[4096];
  const int tid = threadIdx.x, lane = tid & 63, w = tid >> 6;
  const int wr = w >> 1, wc = w & 1;
  const long m0 = (long)blockIdx.y * 128, n0 = (long)blockIdx.x * 128;
  f32x4 zz = {0.f, 0.f, 0.f, 0.f};
  f32x4 acc[4][4];
#pragma unroll
  for (int i = 0; i < 4; ++i)
#pragma unroll
    for (int j = 0; j < 4; ++j) acc[i][j] = zz;

  const int srow = tid >> 2, scol = (tid & 3) * 8;
  const short* Ag = A + (m0 + srow) * K + scol;
  const short* Bg = Bm + (n0 + srow) * K + scol;
  short* Alw = &Al[w * 512];
  short* Blw = &Bl[w * 512];
  const int la = (lane & 15) * 32 + (lane >> 4) * 8;

  for (int k0 = 0; k0 < K; k0 += 32) {
    __syncthreads();
    gl16(Ag + k0, Alw);
    gl16(Ag + (long)64 * K + k0, Alw + 2048);
    gl16(Bg + k0, Blw);
    gl16(Bg + (long)64 * K + k0, Blw + 2048);
    __syncthreads();
    bf16x8 af[4], bfr[4];
#pragma unroll
    for (int mi = 0; mi < 4; ++mi) af[mi] = *(const bf16x8*)&Al[(wr * 64 + mi * 16) * 32 + la];
#pragma unroll
    for (int ni = 0; ni < 4; ++ni) bfr[ni] = *(const bf16x8*)&Bl[(wc * 64 + ni * 16) * 32 + la];
#pragma unroll
    for (int mi = 0; mi < 4; ++mi)
#pragma unroll
      for (int ni = 0; ni < 4; ++ni)
        acc[mi][ni] = __builtin_amdgcn_mfma_f32_16x16x32_bf16(af[mi], bfr[ni], acc[mi][ni], 0, 0, 0);
  }

  if constexpr (MODE == 0) {
    if (wr == 1) return;
#pragma unroll
    for (int mi = 0; mi < 4; ++mi) {
#pragma unroll
      for (int ni = 0; ni < 4; ++ni) {
        int n = (int)n0 + wc * 64 + ni * 16 + (lane & 15);
#pragma unroll
        for (int reg = 0; reg < 4; ++reg) {
          int m = mi * 16 + (lane >> 4) * 4 + reg;
          float v = acc[mi][ni][reg];
          if (n < 512) {
            float r = v * (1.f / 196.f) + b0[n];
            f0[m * 512 + n] = r;
            sb[m * 512 + n] = f2bf(r);
          } else if (n < 1024) {
            int nn = n - 512;
            float r = v * (1.f / 196.f) + b1[nn];
            f1[m * 512 + nn] = r;
          } else {
            int nn = n - 1024;
            f2[(long)nn * 64 + m] = v + b2[nn] + b3[nn];  // ENCCT[row][b]
          }
        }
      }
    }
  }
  if constexpr (MODE == 1) {
#pragma unroll
    for (int mi = 0; mi < 4; ++mi) {
#pragma unroll
      for (int reg = 0; reg < 4; ++reg) {
        long m = m0 + wr * 64 + mi * 16 + (lane >> 4) * 4 + reg;
        if (m < (long)B_ * TDEC) {
          int b = (int)(m / TDEC);
          int t = (int)(m - (long)b * TDEC);
          unsigned short* dst = sb + (long)t * 2048 * 64;
#pragma unroll
          for (int ni = 0; ni < 4; ++ni) {
            int n = (int)n0 + wc * 64 + ni * 16 + (lane & 15);
            dst[(long)n * 64 + b] = f2bf(acc[mi][ni][reg]);  // PGT[t][row][b]
          }
        }
      }
    }
  }
  if constexpr (MODE == 2) {
#pragma unroll
    for (int mi = 0; mi < 4; ++mi) {
#pragma unroll
      for (int reg = 0; reg < 4; ++reg) {
        long m = m0 + wr * 64 + mi * 16 + (lane >> 4) * 4 + reg;
        if (m < (long)B_ * TDEC) {
          int b = (int)(m / TDEC);
          int tt = (int)(m - (long)b * TDEC);
          bool act = tt < (caplen[b] - 1);
          float* orow = f0 + m * V_;
#pragma unroll
          for (int ni = 0; ni < 4; ++ni) {
            int n = (int)n0 + wc * 64 + ni * 16 + (lane & 15);
            if (n < V_) orow[n] = act ? (acc[mi][ni][reg] + b0[n]) : 0.f;
          }
        }
      }
    }
  }
}

// ---------- persistent LSTM recurrence ----------
// 32 WGs x 512 thr; WG owns 16 dims x 4 gates (64 W_hh rows, LDS, swizzled).
// Barrier: per-WG flag lines (no contended RMW) + wave-0 parallel poll.
// Hall stores + PGT prefetch overlap the wait region.
__global__ __launch_bounds__(512, 1) void lstm_rec(
    const short* __restrict__ Whhb, const float* __restrict__ ENCCT,
    const unsigned short* __restrict__ PGT, const float* __restrict__ h0f,
    const float* __restrict__ c0f, const int* __restrict__ caplen,
    unsigned short* __restrict__ hbuf, unsigned short* __restrict__ Hall,
    int* __restrict__ flags) {
  __shared__ short Wl[64 * 512];
  const int tid = threadIdx.x, lane = tid & 63, w = tid >> 6;
  const int wg = blockIdx.x, d0 = wg * 16;
  const int br = w >> 1, rc = w & 1;

  // stage W_hh slice, swizzled: row r' <-> Whh row j = g*512 + d0 + rcc*8 + dl
  for (int it = tid; it < 4096; it += 512) {
    int r = it >> 6, c8 = it & 63;
    int g = (r >> 3) & 3, rcc = r >> 5, dl_ = r & 7;
    int j = g * 512 + d0 + rcc * 8 + dl_;
    bf16x8 v = *(const bf16x8*)(Whhb + (long)j * 512 + c8 * 8);
    *(bf16x8*)&Wl[r * 512 + ((c8 * 8) ^ ((r & 7) << 3))] = v;
  }

  const int q = (lane >> 4) & 3, bit3 = (lane >> 3) & 1, dl = lane & 7;
  const int d = d0 + rc * 8 + dl;
  const int b0 = br * 16 + q * 4 + 2 * bit3;
  const int ji = d, jf = 512 + d, jg = 1024 + d, jo = 1536 + d;

  f32x2 ei = *(const f32x2*)(ENCCT + (long)ji * 64 + b0);
  f32x2 ef = *(const f32x2*)(ENCCT + (long)jf * 64 + b0);
  f32x2 eg = *(const f32x2*)(ENCCT + (long)jg * 64 + b0);
  f32x2 eo = *(const f32x2*)(ENCCT + (long)jo * 64 + b0);
  float c_r[2] = {c0f[b0 * 512 + d], c0f[(b0 + 1) * 512 + d]};
  float h_r[2] = {h0f[b0 * 512 + d], h0f[(b0 + 1) * 512 + d]};
  int dlen0 = caplen[b0] - 1, dlen1 = caplen[b0 + 1] - 1;
  __syncthreads();

  const int arow = br * 16 + (lane & 15);
  const int kgo = (lane >> 4) * 8;
  const int r0 = rc * 32 + (lane & 15), r1 = rc * 32 + 16 + (lane & 15);
  const int sw0 = (r0 & 7) << 3, sw1 = (r1 & 7) << 3;

  // PGT prologue (t = 0)
  ushort2 pi = *(const ushort2*)(PGT + (long)ji * 64 + b0);
  ushort2 pf = *(const ushort2*)(PGT + (long)jf * 64 + b0);
  ushort2 pg = *(const ushort2*)(PGT + (long)jg * 64 + b0);
  ushort2 po = *(const ushort2*)(PGT + (long)jo * 64 + b0);

  for (int t = 0; t < TDEC; ++t) {
    const unsigned short* hsrc = hbuf + (t & 1) * 32768;
    bf16x8 av[16];
#pragma unroll
    for (int kk = 0; kk < 16; ++kk)
      av[kk] = *(const bf16x8*)(hsrc + arow * 512 + kk * 32 + kgo);
    f32x4 a0A = {0.f, 0.f, 0.f, 0.f}, a0B = a0A, a1A = a0A, a1B = a0A;
#pragma unroll
    for (int kk = 0; kk < 8; ++kk) {
      int kA = kk * 32 + kgo, kB = (kk + 8) * 32 + kgo;
      a0A = __builtin_amdgcn_mfma_f32_16x16x32_bf16(
          av[kk], *(const bf16x8*)&Wl[r0 * 512 + (kA ^ sw0)], a0A, 0, 0, 0);
      a1A = __builtin_amdgcn_mfma_f32_16x16x32_bf16(
          av[kk], *(const bf16x8*)&Wl[r1 * 512 + (kA ^ sw1)], a1A, 0, 0, 0);
      a0B = __builtin_amdgcn_mfma_f32_16x16x32_bf16(
          av[kk + 8], *(const bf16x8*)&Wl[r0 * 512 + (kB ^ sw0)], a0B, 0, 0, 0);
      a1B = __builtin_amdgcn_mfma_f32_16x16x32_bf16(
          av[kk + 8], *(const bf16x8*)&Wl[r1 * 512 + (kB ^ sw1)], a1B, 0, 0, 0);
    }
    f32x4 a0 = a0A + a0B, a1 = a1A + a1B;

    float own00 = bit3 ? a0[2] : a0[0], own01 = bit3 ? a0[3] : a0[1];
    float snd00 = bit3 ? a0[0] : a0[2], snd01 = bit3 ? a0[1] : a0[3];
    float own10 = bit3 ? a1[2] : a1[0], own11 = bit3 ? a1[3] : a1[1];
    float snd10 = bit3 ? a1[0] : a1[2], snd11 = bit3 ? a1[1] : a1[3];
    float rcv00 = __shfl_xor(snd00, 8, 64), rcv01 = __shfl_xor(snd01, 8, 64);
    float rcv10 = __shfl_xor(snd10, 8, 64), rcv11 = __shfl_xor(snd11, 8, 64);
    float iv[2], fv[2], gv[2], ov[2];
    iv[0] = bit3 ? rcv00 : own00; iv[1] = bit3 ? rcv01 : own01;
    fv[0] = bit3 ? own00 : rcv00; fv[1] = bit3 ? own01 : rcv01;
    gv[0] = bit3 ? rcv10 : own10; gv[1] = bit3 ? rcv11 : own11;
    ov[0] = bit3 ? own10 : rcv10; ov[1] = bit3 ? own11 : rcv11;

    unsigned short* hdst = hbuf + ((t + 1) & 1) * 32768;
    unsigned short hall0, hall1;
#pragma unroll
    for (int r = 0; r < 2; ++r) {
      float ii = iv[r] + ei[r] + bf2f(r ? pi.y : pi.x);
      float ff = fv[r] + ef[r] + bf2f(r ? pf.y : pf.x);
      float gg = gv[r] + eg[r] + bf2f(r ? pg.y : pg.x);
      float oo = ov[r] + eo[r] + bf2f(r ? po.y : po.x);
      ii = sigm(ii); ff = sigm(ff); oo = sigm(oo); gg = tanh_fast(gg);
      float cn = ff * c_r[r] + ii * gg;
      float hn = oo * tanh_fast(cn);
      bool act = t < (r ? dlen1 : dlen0);
      if (act) { c_r[r] = cn; h_r[r] = hn; }
      hdst[(b0 + r) * 512 + d] = f2bf(h_r[r]);
      unsigned short hb = f2bf(hn);
      if (r == 0) hall0 = hb; else hall1 = hb;
    }

    if (t < TDEC - 1) {
      __syncthreads();  // all waves' hbuf stores complete (waitcnt before barrier)
      if (w == 0 && lane == 0)
        __hip_atomic_store(&flags[wg * 32], t + 1, __ATOMIC_RELEASE,
                           __HIP_MEMORY_SCOPE_AGENT);
      // deferred Hall stores — drain overlaps the poll
      Hall[((long)b0 * TDEC + t) * 512 + d] = hall0;
      Hall[((long)(b0 + 1) * TDEC + t) * 512 + d] = hall1;
      // prefetch PGT for t+1 (immutable input; no fence needed)
      {
        const unsigned short* pgt1 = PGT + (long)(t + 1) * 2048 * 64;
        pi = *(const ushort2*)(pgt1 + (long)ji * 64 + b0);
        pf = *(const ushort2*)(pgt1 + (long)jf * 64 + b0);
        pg = *(const ushort2*)(pgt1 + (long)jg * 64 + b0);
        po = *(const ushort2*)(pgt1 + (long)jo * 64 + b0);
      }
      if (w == 0) {
        if (lane < NWG) {
          while (__hip_atomic_load(&flags[lane * 32], __ATOMIC_RELAXED,
                                   __HIP_MEMORY_SCOPE_AGENT) <= t)
            __builtin_amdgcn_s_sleep(1);
        }
        (void)__hip_atomic_load(&flags[0], __ATOMIC_ACQUIRE, __HIP_MEMORY_SCOPE_AGENT);
      }
      __syncthreads();
    } else {
      Hall[((long)b0 * TDEC + t) * 512 + d] = hall0;
      Hall[((long)(b0 + 1) * TDEC + t) * 512 + d] = hall1;
    }
  }
}

// ---------- host ----------
extern "C" void kernel_launch(void* const* d_in, const int* in_sizes, int n_in,
                              void* d_out, int out_size, void* d_ws, size_t ws_size,
                              hipStream_t stream) {
  const float* enc = (const float*)d_in[0];
  const int* caps = (const int*)d_in[1];
  const int* clen = (const int*)d_in[2];
  const float* emb = (const float*)d_in[3];
  const float* Wih = (const float*)d_in[4];
  const float* bih = (const float*)d_in[5];
  const float* Whh = (const float*)d_in[6];
  const float* bhh = (const float*)d_in[7];
  const float* Wh0 = (const float*)d_in[8];
  const float* bh0 = (const float*)d_in[9];
  const float* Wc0 = (const float*)d_in[10];
  const float* bc0 = (const float*)d_in[11];
  const float* Wfc = (const float*)d_in[12];
  const float* bfc = (const float*)d_in[13];
  float* out = (float*)d_out;

  char* ws = (char*)d_ws;
  size_t off = 0;
  auto alloc = [&](size_t bytes) {
    void* p = ws + off;
    off = (off + bytes + 255) & ~(size_t)255;
    return p;
  };
  int* flags = (int*)alloc(4096);
  unsigned short* App = (unsigned short*)alloc(128L * 1536 * 2);
  short* Wcat = (short*)alloc(3072L * 1536 * 2);
  short* Wihe = (short*)alloc(2048L * 512 * 2);
  short* Whhb = (short*)alloc(2048L * 512 * 2);
  short* Wfcb = (short*)alloc(10112L * 512 * 2);
  short* Xemb = (short*)alloc(4096L * 512 * 2);
  unsigned short* PGT = (unsigned short*)alloc(63L * 2048 * 64 * 2);
  float* ENCCT = (float*)alloc(2048L * 64 * 4);
  float* h0f = (float*)alloc(64L * 512 * 4);
  float* c0f = (float*)alloc(64L * 512 * 4);
  unsigned short* hbuf = (unsigned short*)alloc(2L * 64 * 512 * 2);
  unsigned short* Hall = (unsigned short*)alloc(4096L * 512 * 2);
  (void)ws_size; (void)in_sizes; (void)n_in; (void)out_size;

  hipMemsetAsync(flags, 0, 4096, stream);
  enc_reduce<<<dim3(64, 2), 256, 0, stream>>>(enc, App);
  prep<<<2048, 256, 0, stream>>>(Wh0, Wc0, Wih, Whh, Wfc, emb, caps, Wcat, Wihe, Whhb,
                                 Wfcb, Xemb, Hall, App);
  gemm128<0><<<dim3(24, 1), 256, 0, stream>>>((const short*)App, Wcat, 1536, h0f, c0f,
                                              ENCCT, hbuf, bh0, bc0, bih, bhh, nullptr);
  gemm128<1><<<dim3(16, 32), 256, 0, stream>>>(Xemb, Wihe, 512, nullptr, nullptr, nullptr,
                                               PGT, nullptr, nullptr, nullptr, nullptr,
                                               nullptr);
  lstm_rec<<<dim3(NWG), 512, 0, stream>>>(Whhb, ENCCT, PGT, h0f, c0f, clen, hbuf, Hall,
                                          flags);
  gemm128<2><<<dim3(79, 32), 256, 0, stream>>>((const short*)Hall, Wfcb, 512, out, nullptr,
                                               nullptr, nullptr, bfc, nullptr, nullptr,
                                               nullptr, clen);
}